// Round 4
// baseline (1651.062 us; speedup 1.0000x reference)
//
#include <hip/hip_runtime.h>
#include <math.h>

#define NB 64
#define NN 1024
#define NC 558
#define CP1 559
#define NITERS 20
#define NCOL 576         // padded column count (16 groups x 36)
#define CPL 36           // columns per lane
#define SSTR 592         // staging row stride (576 + 16) -> breaks bank aliasing
#define NSLAB 4          // blocks per batch
#define ROWS_PB 256      // rows per block

// d_ws is poisoned 0xAA before every launch -> re-zero barrier counters
__global__ void zero_cnt_kernel(unsigned int* cnt) {
    int t = blockIdx.x * blockDim.x + threadIdx.x;
    if (t < NB * 16) cnt[t] = 0u;
}

__device__ __forceinline__ float blo(unsigned p) { return __uint_as_float(p << 16); }
__device__ __forceinline__ float bhi(unsigned p) { return __uint_as_float(p & 0xffff0000u); }
__device__ __forceinline__ unsigned rne16(float x) {   // f32 -> bf16 (RNE), finite >=0 inputs
    unsigned a = __float_as_uint(x);
    return (a + 0x7fffu + ((a >> 16) & 1u)) >> 16;
}

// ---------------------------------------------------------------------------
// Persistent exp-domain Sinkhorn, K resident in registers as packed bf16x2.
// Grid: 256 blocks x 512 threads = 1 block/CU (8 waves, 256 VGPR budget).
// 4 blocks per batch, each owns a 256-row slab.
// Lane layout: lane = cg + 16*rl (cg: 16 col-groups of 36 cols; rl: 4 row
// groups). Each lane: 8 rows x 36 cols = 144 packed bf16x2 regs + v[36] f32.
// u-phase: 36 fma/row + butterfly over cg (xor 1,2,4,8).
// v-phase: per-lane accumulate over its 8 rows (zero shfl) + 2-level tree
//          over rl (xor 16,32) + cross-wave LDS + cross-block exchange
//          (double-buffered gpart + one atomic-counter barrier per iter).
// visible_mask layout (bool8 / int32 / f32) auto-detected at runtime.
// ---------------------------------------------------------------------------
__global__ __launch_bounds__(512, 2)
void sinkhorn_kernel(const float* __restrict__ logits,
                     const unsigned char* __restrict__ vis,
                     const float* __restrict__ dustp,
                     float* __restrict__ out,
                     float* __restrict__ gpart,       // [NB][2][NSLAB][NCOL]
                     unsigned int* __restrict__ cnt)  // [NB*16]
{
    const int tid = (int)threadIdx.x;
    const int blk = (int)blockIdx.x;
    // blk = xcd + 8*(s + 4*bgrp): 4 slabs of a batch share an XCD (perf only)
    const int s   = (blk >> 3) & 3;
    const int b   = (blk & 7) * 8 + (blk >> 5);
    const int w   = tid >> 6;
    const int l   = tid & 63;
    const int cg  = l & 15;
    const int rl  = l >> 4;
    const int n0  = s * ROWS_PB + w * 32 + rl * 8;   // lane's row for k=0

    __shared__ float v_lds[NCOL];
    __shared__ float wavepart[8][NCOL];
    __shared__ __align__(16) float stage[8][4 * SSTR];
    __shared__ float red[512];
    __shared__ float nv_sh;
    __shared__ int wide_sh;

    // ---------- mask layout detection (1-byte bool vs 4-byte int/f32) ----------
    // Wide layouts: every u32 word is 0, 1, or 0x3F800000 (1.0f). Byte-packed
    // bool at ~90% density cannot have all 512 sampled words in that set.
    {
        unsigned word = ((const unsigned*)vis)[tid];   // first 2 KiB, in bounds
        int odd = !(word == 0u || word == 1u || word == 0x3F800000u);
        if (tid == 0) wide_sh = 1;
        __syncthreads();
        if (odd) wide_sh = 0;          // benign race: all writers store 0
        __syncthreads();
    }
    const bool wide = (wide_sh != 0);
    const unsigned* vw = (const unsigned*)vis;
    auto visnz = [&](int idx) -> int {
        return wide ? (vw[idx] != 0u) : (vis[idx] != 0);
    };

    // ---------- nv = sum(visible_mask[b]) ----------
    red[tid] = (float)(visnz(b * NN + 2 * tid) + visnz(b * NN + 2 * tid + 1));
    __syncthreads();
    #pragma unroll
    for (int off = 256; off > 0; off >>= 1) {
        if (tid < off) red[tid] += red[tid + off];
        __syncthreads();
    }
    if (tid == 0) nv_sh = fmaxf(red[0], 1.0f);
    __syncthreads();
    const float inv_nv = __builtin_amdgcn_rcpf(nv_sh);
    const float nu = 1.0f / (float)CP1;

    unsigned vmask = 0;   // bit k: row n0+k visible
    #pragma unroll
    for (int k = 0; k < 8; k++)
        vmask |= (unsigned)visnz(b * NN + n0 + k) << k;

    const float dustk = __expf(dustp[0]);

    unsigned kpk[8][18];   // packed bf16x2: row k, col pair ci -> cols 2ci,2ci+1
    float vv[CPL];         // v for this lane's 36 cols (reused as acc in v-phase)

    // ---------- load (coalesced via LDS) + row-softmax + bf16 pack ----------
    // chunk k: stage rows (w*32 + q*8 + k), q=0..3; lane consumes section q==rl.
    #pragma unroll
    for (int k = 0; k < 8; k++) {
        #pragma unroll
        for (int q = 0; q < 4; q++) {
            const float2* gp2 = (const float2*)(logits +
                (size_t)(b * NN + s * ROWS_PB + w * 32 + q * 8 + k) * NC);
            float2* st2 = (float2*)&stage[w][q * SSTR];
            #pragma unroll
            for (int i = 0; i < 5; i++) {
                int idx = l + i * 64;
                if (idx < NC / 2) st2[idx] = gp2[idx];
            }
        }
        __builtin_amdgcn_wave_barrier();
        float raw[CPL];
        #pragma unroll
        for (int i4 = 0; i4 < 9; i4++) {
            float4 qv = *(const float4*)&stage[w][rl * SSTR + cg * CPL + 4 * i4];
            raw[4*i4+0] = qv.x; raw[4*i4+1] = qv.y;
            raw[4*i4+2] = qv.z; raw[4*i4+3] = qv.w;
        }
        __builtin_amdgcn_wave_barrier();
        if (cg == 15) {                       // cols 558..575: dustbin+pad slots
            #pragma unroll
            for (int i = 18; i < CPL; i++) raw[i] = -INFINITY;
        }
        float mx = -INFINITY;
        #pragma unroll
        for (int i = 0; i < CPL; i++) mx = fmaxf(mx, raw[i]);
        mx = fmaxf(mx, __shfl_xor(mx, 1));
        mx = fmaxf(mx, __shfl_xor(mx, 2));
        mx = fmaxf(mx, __shfl_xor(mx, 4));
        mx = fmaxf(mx, __shfl_xor(mx, 8));
        float ssum = 0.0f;
        #pragma unroll
        for (int i = 0; i < CPL; i++) { float e = __expf(raw[i] - mx); raw[i] = e; ssum += e; }
        ssum += __shfl_xor(ssum, 1);
        ssum += __shfl_xor(ssum, 2);
        ssum += __shfl_xor(ssum, 4);
        ssum += __shfl_xor(ssum, 8);
        const float isum = __builtin_amdgcn_rcpf(ssum);
        #pragma unroll
        for (int ci = 0; ci < 18; ci++)
            kpk[k][ci] = rne16(raw[2*ci] * isum) | (rne16(raw[2*ci+1] * isum) << 16);
        if (cg == 15)   // col 558 = dustbin (unnormalized exp(dust)); pads stay 0
            kpk[k][9] = (kpk[k][9] & 0xffff0000u) | rne16(dustk);
    }

    // ---------- v init: 1 for real cols, 0 for pads ----------
    #pragma unroll
    for (int i = 0; i < CPL; i++) vv[i] = (cg * CPL + i < CP1) ? 1.0f : 0.0f;

    float u[8];
    const bool bb16 = (l & 16) != 0, bb32 = (l & 32) != 0;
    const int off9 = (bb16 ? 18 : 0) + (bb32 ? 9 : 0);

    // ---------- Sinkhorn iterations ----------
    #pragma unroll 1
    for (int t = 1; t <= NITERS; t++) {
        // u-phase: u_k = mu_k / (K v) per row
        #pragma unroll
        for (int k = 0; k < 8; k++) {
            float d0 = 0.0f, d1 = 0.0f;
            #pragma unroll
            for (int ci = 0; ci < 18; ci++) {
                unsigned p = kpk[k][ci];
                d0 = fmaf(blo(p), vv[2*ci],   d0);
                d1 = fmaf(bhi(p), vv[2*ci+1], d1);
            }
            float d = d0 + d1;
            d += __shfl_xor(d, 1);
            d += __shfl_xor(d, 2);
            d += __shfl_xor(d, 4);
            d += __shfl_xor(d, 8);
            float muk = ((vmask >> k) & 1u) ? inv_nv : 0.0f;
            u[k] = muk * __builtin_amdgcn_rcpf(d);
        }
        // v-phase: colsum = K^T u; vv becomes the accumulator
        #pragma unroll
        for (int i = 0; i < CPL; i++) vv[i] = 0.0f;
        #pragma unroll
        for (int k = 0; k < 8; k++) {
            #pragma unroll
            for (int ci = 0; ci < 18; ci++) {
                unsigned p = kpk[k][ci];
                vv[2*ci]   = fmaf(blo(p), u[k], vv[2*ci]);
                vv[2*ci+1] = fmaf(bhi(p), u[k], vv[2*ci+1]);
            }
        }
        // tree over rl: xor16 then xor32 -> 9 cols per lane
        float t18[18];
        #pragma unroll
        for (int i = 0; i < 18; i++) {
            float kept = bb16 ? vv[i + 18] : vv[i];
            float oth  = bb16 ? vv[i]      : vv[i + 18];
            t18[i] = kept + __shfl_xor(oth, 16);
        }
        float t9[9];
        #pragma unroll
        for (int i = 0; i < 9; i++) {
            float kept = bb32 ? t18[i + 9] : t18[i];
            float oth  = bb32 ? t18[i]     : t18[i + 9];
            t9[i] = kept + __shfl_xor(oth, 32);
        }
        #pragma unroll
        for (int i = 0; i < 9; i++)
            wavepart[w][cg * CPL + off9 + i] = t9[i];
        __syncthreads();
        // cross-wave combine + publish slab partial (device scope)
        const int pbase = ((b * 2 + (t & 1)) * NSLAB) * NCOL;
        #pragma unroll
        for (int c0 = 0; c0 < NCOL; c0 += 512) {
            int c = c0 + tid;
            if (c < NCOL) {
                float a = 0.0f;
                #pragma unroll
                for (int ww = 0; ww < 8; ww++) a += wavepart[ww][c];
                __hip_atomic_store(&gpart[pbase + s * NCOL + c], a,
                                   __ATOMIC_RELAXED, __HIP_MEMORY_SCOPE_AGENT);
            }
        }
        __syncthreads();
        // one barrier per iteration among the 4 blocks of this batch
        if (tid == 0) {
            __hip_atomic_fetch_add(&cnt[b * 16], 1u,
                                   __ATOMIC_ACQ_REL, __HIP_MEMORY_SCOPE_AGENT);
            const unsigned tgt = 4u * (unsigned)t;
            while (__hip_atomic_load(&cnt[b * 16],
                                     __ATOMIC_ACQUIRE, __HIP_MEMORY_SCOPE_AGENT) < tgt)
                __builtin_amdgcn_s_sleep(1);
        }
        __syncthreads();
        // combine 4 slabs -> v = nu / colsum (pads -> 0)
        #pragma unroll
        for (int c0 = 0; c0 < NCOL; c0 += 512) {
            int c = c0 + tid;
            if (c < NCOL) {
                float tot = 0.0f;
                #pragma unroll
                for (int ss = 0; ss < NSLAB; ss++)
                    tot += __hip_atomic_load(&gpart[pbase + ss * NCOL + c],
                                             __ATOMIC_RELAXED, __HIP_MEMORY_SCOPE_AGENT);
                v_lds[c] = (c < CP1) ? nu * __builtin_amdgcn_rcpf(tot) : 0.0f;
            }
        }
        __syncthreads();
        // refill this lane's v slice
        #pragma unroll
        for (int i4 = 0; i4 < 9; i4++) {
            float4 qv = *(const float4*)&v_lds[cg * CPL + 4 * i4];
            vv[4*i4+0] = qv.x; vv[4*i4+1] = qv.y;
            vv[4*i4+2] = qv.z; vv[4*i4+3] = qv.w;
        }
    }

    // ---------- epilogue: P = K * u * v (coalesced via LDS) ----------
    #pragma unroll
    for (int k = 0; k < 8; k++) {
        #pragma unroll
        for (int ci = 0; ci < 18; ci++) {
            unsigned p = kpk[k][ci];
            stage[w][rl * SSTR + cg * CPL + 2*ci]     = blo(p) * u[k] * vv[2*ci];
            stage[w][rl * SSTR + cg * CPL + 2*ci + 1] = bhi(p) * u[k] * vv[2*ci+1];
        }
        __builtin_amdgcn_wave_barrier();
        #pragma unroll
        for (int q = 0; q < 4; q++) {
            float* gp = out + (size_t)(b * NN + s * ROWS_PB + w * 32 + q * 8 + k) * CP1;
            #pragma unroll
            for (int i = 0; i < 9; i++) {
                int c = l + i * 64;
                if (c < CP1) gp[c] = stage[w][q * SSTR + c];
            }
        }
        __builtin_amdgcn_wave_barrier();
    }
}

extern "C" void kernel_launch(void* const* d_in, const int* in_sizes, int n_in,
                              void* d_out, int out_size, void* d_ws, size_t ws_size,
                              hipStream_t stream)
{
    const float* logits      = (const float*)d_in[0];
    const unsigned char* vis = (const unsigned char*)d_in[1];
    const float* dustp       = (const float*)d_in[2];
    float* out               = (float*)d_out;

    // workspace: gpart [64][2][4][576] f32 = 1,179,648 B, then counters 4 KB
    float* gpart      = (float*)d_ws;
    unsigned int* cnt = (unsigned int*)((char*)d_ws +
                         (size_t)NB * 2 * NSLAB * NCOL * sizeof(float));

    zero_cnt_kernel<<<1, 1024, 0, stream>>>(cnt);
    sinkhorn_kernel<<<256, 512, 0, stream>>>(logits, vis, dustp, out, gpart, cnt);
}